// Round 11
// baseline (197.318 us; speedup 1.0000x reference)
//
#include <hip/hip_runtime.h>
#include <hip/hip_bf16.h>
#include <math.h>

// N=10000, E=160000, DIN=DOUT=256. edge_index is int32 (verified R4/R5).
#define D 256
#define CAP 128           // per-node edge slots; max degree ~45 for this graph
#define NEG_SLOPE 0.2f
#define BN_EPS 1e-5f
#define NBKT 64           // BN column-sum buckets (39 atomics/address — R12 lesson)

typedef __attribute__((ext_vector_type(8))) short bf16x8;
typedef __attribute__((ext_vector_type(8))) unsigned short ushort8;
typedef __attribute__((ext_vector_type(4))) unsigned short ushort4v;
typedef __attribute__((ext_vector_type(4))) float f32x4;

__device__ inline unsigned short f2bf(float f) {
    union { float f; unsigned u; } v; v.f = f;
    unsigned u = v.u;
    unsigned r = u + 0x7FFFu + ((u >> 16) & 1u);   // RNE
    return (unsigned short)(r >> 16);
}
__device__ inline float bf2f(unsigned short u) {
    union { unsigned u; float f; } v; v.u = ((unsigned)u) << 16; return v.f;
}

// async global->LDS, 16B per lane; LDS dest linear, swizzle pre-applied to the
// GLOBAL layout (m173 both-sides-or-neither pattern).
__device__ __forceinline__ void gload16(const void* g, void* l) {
    __builtin_amdgcn_global_load_lds(
        (const __attribute__((address_space(1))) unsigned int*)g,
        (__attribute__((address_space(3))) unsigned int*)l,
        16, 0, 0);
}

// ---------------------------------------------------------------------------
// prep: blocks [0,nzb) zero bsum+bsq+counts; [nzb,nzb+128) Bt transpose via
// LDS 32x32 tiles; [nzb+128,...) X fp32->bf16 (XOR-swizzled, zero-padded to
// Mpad rows). Swizzle: k ^= ((row & 7) << 3) — conflict-free ds_read_b128.
// ---------------------------------------------------------------------------
__global__ void prep_kernel(const float* __restrict__ X,
                            const float* __restrict__ Wl, const float* __restrict__ Wr,
                            int* __restrict__ zero_base, int nzero, int nzb,
                            unsigned short* __restrict__ Bt,
                            unsigned short* __restrict__ Xbf, int N) {
    int b = blockIdx.x;
    if (b < nzb) {
        int idx = b * 256 + threadIdx.x;
        if (idx < nzero) zero_base[idx] = 0;
    } else if (b < nzb + 128) {
        __shared__ float tile[32][33];
        int b2 = b - nzb;                 // 0..127
        const float* W = (b2 < 64) ? Wl : Wr;
        int nbase = (b2 < 64) ? 0 : 256;
        int t2 = b2 & 63;
        int ti = t2 >> 3;                 // k-tile 0..7
        int tj = t2 & 7;                  // n-tile 0..7
        int t = threadIdx.x;
        int r = t >> 3;                   // 0..31
        int c4 = (t & 7) * 4;             // 0..28
        float4 v = *(const float4*)(W + (size_t)(ti * 32 + r) * 256 + tj * 32 + c4);
        tile[r][c4] = v.x; tile[r][c4 + 1] = v.y;
        tile[r][c4 + 2] = v.z; tile[r][c4 + 3] = v.w;
        __syncthreads();
        int nl = t >> 3;
        int n = tj * 32 + nl;
        int k0 = ti * 32 + c4;
        int ks = k0 ^ ((n & 7) << 3);
        ushort4v o;
        o[0] = f2bf(tile[c4][nl]);
        o[1] = f2bf(tile[c4 + 1][nl]);
        o[2] = f2bf(tile[c4 + 2][nl]);
        o[3] = f2bf(tile[c4 + 3][nl]);
        *(ushort4v*)(Bt + (size_t)(nbase + n) * 256 + ks) = o;
    } else {
        int idx = (b - nzb - 128) * 256 + threadIdx.x;   // one 16B chunk (8 elems)
        int row = idx >> 5;
        int k0 = (idx & 31) * 8;
        int ks = k0 ^ ((row & 7) << 3);
        ushort8 v = {0, 0, 0, 0, 0, 0, 0, 0};
        if (row < N) {
            const float* src = X + (size_t)row * 256 + k0;
            float4 f0 = *(const float4*)(src);
            float4 f1 = *(const float4*)(src + 4);
            v[0] = f2bf(f0.x); v[1] = f2bf(f0.y);
            v[2] = f2bf(f0.z); v[3] = f2bf(f0.w);
            v[4] = f2bf(f1.x); v[5] = f2bf(f1.y);
            v[6] = f2bf(f1.z); v[7] = f2bf(f1.w);
        }
        *(ushort8*)(Xbf + (size_t)row * 256 + ks) = v;   // pad rows -> zeros
    }
}

// ---------------------------------------------------------------------------
// gemm_scatter: blocks [0,ngemm) = 64x64 MFMA GEMM tiles with XCD-affinity
// swizzle; staging pure global_load_lds width-16 into linear LDS (swizzle
// baked into the global layout). xl AND xr outputs bf16.
// blocks [ngemm,...) = per-dst edge scatter.
// ---------------------------------------------------------------------------
__global__ __launch_bounds__(256) void gemm_scatter_kernel(
    const unsigned short* __restrict__ Xbf, const unsigned short* __restrict__ Bt,
    const float* __restrict__ bl, const float* __restrict__ br,
    const int* __restrict__ ei, int* __restrict__ counts, int* __restrict__ ssrc,
    unsigned short* __restrict__ xlbf, unsigned short* __restrict__ xrbf,
    int M, int E, int N, int ngemm, int nMtiles)
{
    if ((int)blockIdx.x >= ngemm) {
        int e = (blockIdx.x - ngemm) * 256 + threadIdx.x;
        if (e < E + N) {
            int src, dst;
            if (e < E) { src = ei[e]; dst = ei[E + e]; }
            else       { src = dst = e - E; }          // self-loop
            int pos = atomicAdd(&counts[dst], 1);
            if (pos < CAP) ssrc[dst * CAP + pos] = src;
        }
        return;
    }

    const int b = blockIdx.x;
    const int r = (b & 7) + 8 * (b >> 6);           // row-tile
    const int c = (b >> 3) & 7;                     // col-tile 0..7
    if (r >= nMtiles) return;

    __shared__ __align__(16) unsigned short As[64 * 128];
    __shared__ __align__(16) unsigned short Bs[64 * 128];

    const int tid = threadIdx.x;
    const int wave = tid >> 6, lane = tid & 63;
    const int m_l = lane & 15, quad = lane >> 4;
    const int row0 = r * 64;
    const int n0 = c * 64;
    const int sw = (m_l & 7) << 3;

    f32x4 acc[4] = {};

    for (int k0 = 0; k0 < 256; k0 += 128) {
        __syncthreads();
        #pragma unroll
        for (int i = 0; i < 4; i++) {
            int L = (tid + i * 256) * 16;
            int rr = L >> 8;
            int cb = L & 255;
            gload16((const char*)Xbf + (size_t)(row0 + rr) * 512 + (size_t)k0 * 2 + cb,
                    (char*)As + L);
            gload16((const char*)Bt + (size_t)(n0 + rr) * 512 + (size_t)k0 * 2 + cb,
                    (char*)Bs + L);
        }
        __syncthreads();

        #pragma unroll
        for (int kk0 = 0; kk0 < 128; kk0 += 32) {
            int ka = (kk0 + quad * 8) ^ sw;
            bf16x8 a = *(const bf16x8*)&As[(wave * 16 + m_l) * 128 + ka];
            #pragma unroll
            for (int cc = 0; cc < 4; cc++) {
                bf16x8 bv = *(const bf16x8*)&Bs[(cc * 16 + m_l) * 128 + ka];
                acc[cc] = __builtin_amdgcn_mfma_f32_16x16x32_bf16(a, bv, acc[cc], 0, 0, 0);
            }
        }
    }

    const bool isl = (n0 < 256);
    #pragma unroll
    for (int cc = 0; cc < 4; cc++) {
        int col = n0 + cc * 16 + m_l;
        int col8 = col & 255;
        float bv = isl ? bl[col8] : br[col8];
        #pragma unroll
        for (int rr = 0; rr < 4; rr++) {
            int row = row0 + wave * 16 + quad * 4 + rr;
            if (row < M) {
                float v = acc[cc][rr] + bv;
                if (isl) xlbf[(size_t)row * 256 + col8] = f2bf(v);
                else     xrbf[(size_t)row * 256 + col8] = f2bf(v);
            }
        }
    }
}

// ---------------------------------------------------------------------------
// node: ONE NODE PER WAVE, direct-exp softmax, bf16 xr, register adjacency +
// shfl addressing (R10-best body, unchanged math). NEW: `reps` outer loop —
// the real pass runs reps=1 (identical to R10); a probe pass runs reps=2 into
// scratch buffers, producing a ~60 µs dispatch that clears the harness-fill
// 44 µs top-5 bar and finally yields per-kernel counters for node.
// ---------------------------------------------------------------------------
__device__ __forceinline__ float dot8leakyc(ushort8 c, float4 bA, float4 bB,
                                            float4 aA, float4 aB) {
    float h, s = 0.f;
    h = bf2f(c[0]) + bA.x; h = (h > 0.f) ? h : NEG_SLOPE * h; s += h * aA.x;
    h = bf2f(c[1]) + bA.y; h = (h > 0.f) ? h : NEG_SLOPE * h; s += h * aA.y;
    h = bf2f(c[2]) + bA.z; h = (h > 0.f) ? h : NEG_SLOPE * h; s += h * aA.z;
    h = bf2f(c[3]) + bA.w; h = (h > 0.f) ? h : NEG_SLOPE * h; s += h * aA.w;
    h = bf2f(c[4]) + bB.x; h = (h > 0.f) ? h : NEG_SLOPE * h; s += h * aB.x;
    h = bf2f(c[5]) + bB.y; h = (h > 0.f) ? h : NEG_SLOPE * h; s += h * aB.y;
    h = bf2f(c[6]) + bB.z; h = (h > 0.f) ? h : NEG_SLOPE * h; s += h * aB.z;
    h = bf2f(c[7]) + bB.w; h = (h > 0.f) ? h : NEG_SLOPE * h; s += h * aB.w;
    return s;
}

__global__ __launch_bounds__(256, 4) void node_kernel(
    const unsigned short* __restrict__ xlbf, const unsigned short* __restrict__ xrbf,
    const float* __restrict__ att, const float* __restrict__ bias,
    const float* __restrict__ du, const int* __restrict__ counts,
    const int* __restrict__ ssrc, float* __restrict__ out,
    float* __restrict__ bsum, float* __restrict__ bsq, int N, int reps)
{
    __shared__ float ls[4][256];

    const int wave = threadIdx.x >> 6, lane = threadIdx.x & 63;
    const int i = blockIdx.x * 4 + wave;
    const bool valid = (i < N);
    const int hl = lane & 31;
    const int sid = lane >> 5;                  // stream 0 or 1

    const ushort8 z8 = {0, 0, 0, 0, 0, 0, 0, 0};
    const float4 attA = ((const float4*)att)[hl * 2];
    const float4 attB = ((const float4*)att)[hl * 2 + 1];
    const unsigned short* xb = xlbf + hl * 8;

    for (int rep = 0; rep < reps; ++rep) {
        int cnt = valid ? counts[i] : 0;
        if (cnt > CAP) cnt = CAP;
        const int start = i * CAP, end = start + cnt;

        ushort8 xrv = valid ? *(const ushort8*)(xrbf + (size_t)i * D + hl * 8) : z8;
        float4 bA, bB;
        bA.x = bf2f(xrv[0]); bA.y = bf2f(xrv[1]); bA.z = bf2f(xrv[2]); bA.w = bf2f(xrv[3]);
        bB.x = bf2f(xrv[4]); bB.y = bf2f(xrv[5]); bB.z = bf2f(xrv[6]); bB.w = bf2f(xrv[7]);

        float lsum = 0.f;
        float acc[8] = {0.f, 0.f, 0.f, 0.f, 0.f, 0.f, 0.f, 0.f};

        for (int cs = start; cs < end; cs += 64) {
            const int cend = (end < cs + 64) ? end : cs + 64;
            int srcv = ssrc[cs + lane];         // in-bounds: cs+lane < start+CAP
            int e = cs + sid;

            ushort8 p0, p1, p2, p3;
            {
                int a0 = __shfl(srcv, sid);
                int a1 = __shfl(srcv, sid + 2);
                int a2 = __shfl(srcv, sid + 4);
                int a3 = __shfl(srcv, sid + 6);
                p0 = (e     < cend) ? *(const ushort8*)(xb + (size_t)a0 * D) : z8;
                p1 = (e + 2 < cend) ? *(const ushort8*)(xb + (size_t)a1 * D) : z8;
                p2 = (e + 4 < cend) ? *(const ushort8*)(xb + (size_t)a2 * D) : z8;
                p3 = (e + 6 < cend) ? *(const ushort8*)(xb + (size_t)a3 * D) : z8;
            }

            while (e < cend) {
                ushort8 c0 = p0, c1 = p1, c2 = p2, c3 = p3;
                bool v1 = (e + 2 < cend), v2 = (e + 4 < cend), v3 = (e + 6 < cend);
                int en = e + 8;
                {
                    int on = (en - cs) & 63;
                    int a0 = __shfl(srcv, on);
                    int a1 = __shfl(srcv, on + 2);
                    int a2 = __shfl(srcv, on + 4);
                    int a3 = __shfl(srcv, on + 6);
                    p0 = (en     < cend) ? *(const ushort8*)(xb + (size_t)a0 * D) : z8;
                    p1 = (en + 2 < cend) ? *(const ushort8*)(xb + (size_t)a1 * D) : z8;
                    p2 = (en + 4 < cend) ? *(const ushort8*)(xb + (size_t)a2 * D) : z8;
                    p3 = (en + 6 < cend) ? *(const ushort8*)(xb + (size_t)a3 * D) : z8;
                }

                float s0 = dot8leakyc(c0, bA, bB, attA, attB);
                float s1 = dot8leakyc(c1, bA, bB, attA, attB);
                float s2 = dot8leakyc(c2, bA, bB, attA, attB);
                float s3 = dot8leakyc(c3, bA, bB, attA, attB);

                #pragma unroll
                for (int off = 1; off < 32; off <<= 1) {    // within half-wave
                    s0 += __shfl_xor(s0, off);
                    s1 += __shfl_xor(s1, off);
                    s2 += __shfl_xor(s2, off);
                    s3 += __shfl_xor(s3, off);
                }
                if (!v1) s1 = -INFINITY;                    // exp(-inf) = 0
                if (!v2) s2 = -INFINITY;
                if (!v3) s3 = -INFINITY;

                float e0e = __expf(s0);
                float e1e = __expf(s1);
                float e2e = __expf(s2);
                float e3e = __expf(s3);
                lsum += e0e + e1e + e2e + e3e;
                #pragma unroll
                for (int k = 0; k < 8; k++) {
                    acc[k] += e0e * bf2f(c0[k]) + e1e * bf2f(c1[k])
                            + e2e * bf2f(c2[k]) + e3e * bf2f(c3[k]);
                }
                e = en;
            }
        }

        // du row load: latency hides under the combine shuffles
        float4 uA, uB;
        if (valid && lane < 32) {
            uA = ((const float4*)(du + (size_t)i * D))[hl * 2];
            uB = ((const float4*)(du + (size_t)i * D))[hl * 2 + 1];
        }

        // combine the two half-wave streams (plain adds — direct exp)
        lsum += __shfl_xor(lsum, 32);
        #pragma unroll
        for (int k = 0; k < 8; k++) acc[k] += __shfl_xor(acc[k], 32);

        // epilogue: bias+ReLU+dropout, store, BN staging
        float ov[8];
        if (lane < 32) {
            if (valid) {
                float inv = 1.f / lsum;
                float4 biA = ((const float4*)bias)[hl * 2];
                float4 biB = ((const float4*)bias)[hl * 2 + 1];
                float4 oA, oB;
                oA.x = fmaxf(acc[0] * inv + biA.x, 0.f); oA.x = (uA.x >= 0.5f) ? 2.f * oA.x : 0.f;
                oA.y = fmaxf(acc[1] * inv + biA.y, 0.f); oA.y = (uA.y >= 0.5f) ? 2.f * oA.y : 0.f;
                oA.z = fmaxf(acc[2] * inv + biA.z, 0.f); oA.z = (uA.z >= 0.5f) ? 2.f * oA.z : 0.f;
                oA.w = fmaxf(acc[3] * inv + biA.w, 0.f); oA.w = (uA.w >= 0.5f) ? 2.f * oA.w : 0.f;
                oB.x = fmaxf(acc[4] * inv + biB.x, 0.f); oB.x = (uB.x >= 0.5f) ? 2.f * oB.x : 0.f;
                oB.y = fmaxf(acc[5] * inv + biB.y, 0.f); oB.y = (uB.y >= 0.5f) ? 2.f * oB.y : 0.f;
                oB.z = fmaxf(acc[6] * inv + biB.z, 0.f); oB.z = (uB.z >= 0.5f) ? 2.f * oB.z : 0.f;
                oB.w = fmaxf(acc[7] * inv + biB.w, 0.f); oB.w = (uB.w >= 0.5f) ? 2.f * oB.w : 0.f;
                ((float4*)(out + (size_t)i * D))[hl * 2] = oA;
                ((float4*)(out + (size_t)i * D))[hl * 2 + 1] = oB;
                ov[0] = oA.x; ov[1] = oA.y; ov[2] = oA.z; ov[3] = oA.w;
                ov[4] = oB.x; ov[5] = oB.y; ov[6] = oB.z; ov[7] = oB.w;
            } else {
                #pragma unroll
                for (int k = 0; k < 8; k++) ov[k] = 0.f;
            }
            #pragma unroll
            for (int k = 0; k < 8; k++) ls[wave][hl * 8 + k] = ov[k];
        }
        __syncthreads();

        // per-block column reduction over the 4 rows, one atomic pair/column
        {
            int t = threadIdx.x;
            float s = 0.f, s2 = 0.f;
            #pragma unroll
            for (int w = 0; w < 4; w++) {
                float v = ls[w][t];
                s += v; s2 += v * v;
            }
            int bkt = (blockIdx.x & (NBKT - 1)) * 256 + t;
            atomicAdd(&bsum[bkt], s);
            atomicAdd(&bsq[bkt], s2);
        }
        __syncthreads();    // protect ls before next rep
    }
}

// ---------------------------------------------------------------------------
// bn_apply: 256 blocks, bucket-reduce prologue + in-place FMA.
// ---------------------------------------------------------------------------
__global__ __launch_bounds__(256) void bn_apply_kernel(
    float* __restrict__ out,
    const float* __restrict__ bsum, const float* __restrict__ bsq,
    const float* __restrict__ gamma, const float* __restrict__ beta, int N)
{
    __shared__ float scaleL[256], shiftL[256];
    const int t = threadIdx.x;
    float s = 0.f, s2 = 0.f;
    #pragma unroll 8
    for (int b = 0; b < NBKT; b++) {
        s += bsum[b * 256 + t];
        s2 += bsq[b * 256 + t];
    }
    float invN = 1.f / (float)N;
    float mean = s * invN;
    float var = s2 * invN - mean * mean;
    float rs = rsqrtf(var + BN_EPS);
    float sc = gamma[t] * rs;
    scaleL[t] = sc;
    shiftL[t] = beta[t] - mean * sc;
    __syncthreads();

    const int c4 = t & 63;
    float4 scv, shv;
    scv.x = scaleL[c4 * 4];     shv.x = shiftL[c4 * 4];
    scv.y = scaleL[c4 * 4 + 1]; shv.y = shiftL[c4 * 4 + 1];
    scv.z = scaleL[c4 * 4 + 2]; shv.z = shiftL[c4 * 4 + 2];
    scv.w = scaleL[c4 * 4 + 3]; shv.w = shiftL[c4 * 4 + 3];

    for (int row = blockIdx.x * 4 + (t >> 6); row < N; row += gridDim.x * 4) {
        float4 v = ((float4*)(out + (size_t)row * D))[c4];
        v.x = v.x * scv.x + shv.x;
        v.y = v.y * scv.y + shv.y;
        v.z = v.z * scv.z + shv.z;
        v.w = v.w * scv.w + shv.w;
        ((float4*)(out + (size_t)row * D))[c4] = v;
    }
}

// ---------------------------------------------------------------------------
extern "C" void kernel_launch(void* const* d_in, const int* in_sizes, int n_in,
                              void* d_out, int out_size, void* d_ws, size_t ws_size,
                              hipStream_t stream) {
    const float* x     = (const float*)d_in[0];
    const int*   ei    = (const int*)d_in[1];
    const float* Wl    = (const float*)d_in[2];
    const float* bl    = (const float*)d_in[3];
    const float* Wr    = (const float*)d_in[4];
    const float* br    = (const float*)d_in[5];
    const float* att   = (const float*)d_in[6];
    const float* bias  = (const float*)d_in[7];
    const float* gamma = (const float*)d_in[8];
    const float* beta  = (const float*)d_in[9];
    const float* du    = (const float*)d_in[10];

    const int N = in_sizes[0] / D;       // 10000
    const int E = in_sizes[1] / 2;       // 160000
    const int Mpad = (N + 63) & ~63;     // 10048

    // workspace layout (4-byte word units)
    int* ws = (int*)d_ws;
    size_t off = 0;
    unsigned short* xrbf = (unsigned short*)(ws + off); off += (size_t)N * D / 2;
    unsigned short* xlbf = (unsigned short*)(ws + off); off += (size_t)N * D / 2;
    unsigned short* Xbf  = (unsigned short*)(ws + off); off += (size_t)Mpad * D / 2;
    unsigned short* Bt   = (unsigned short*)(ws + off); off += 512 * 256 / 2;
    int*   ssrc     = ws + off;           off += (size_t)N * CAP;
    // contiguous zeroed region (zeroed by prep_kernel blocks [0,nzb)):
    float* bsum     = (float*)(ws + off); off += NBKT * 256;
    float* bsq      = (float*)(ws + off); off += NBKT * 256;
    int*   counts   = ws + off;           off += N;
    int nzero = 2 * NBKT * 256 + N;      // 42768 words
    int nzb = (nzero + 255) / 256;       // 168 zero blocks
    // scratch for the counter-probe pass (never read):
    float* out2     = (float*)(ws + off); off += (size_t)N * D;
    float* bsum2    = (float*)(ws + off); off += NBKT * 256;
    float* bsq2     = (float*)(ws + off); off += NBKT * 256;

    int nconv = (Mpad * 32) / 256;       // 1256 blocks, 8 elems/thread
    prep_kernel<<<nzb + 128 + nconv, 256, 0, stream>>>(
        x, Wl, Wr, (int*)bsum, nzero, nzb, Bt, Xbf, N);

    int nMtiles = (N + 63) / 64;         // 157
    int nMgroups = (nMtiles + 7) / 8;    // 20
    int ngemm = nMgroups * 64;           // 1280 gemm blocks (24 idle)
    int nscat = (E + N + 255) / 256;     // 665
    gemm_scatter_kernel<<<ngemm + nscat, 256, 0, stream>>>(
        Xbf, Bt, bl, br, ei, counts, ssrc, xlbf, xrbf, N, E, N, ngemm, nMtiles);

    // PROBE: reps=2 into scratch — single ~60 µs dispatch that clears the
    // 44 µs harness-fill bar so node finally shows its counters in top-5.
    node_kernel<<<(N + 3) / 4, 256, 0, stream>>>(
        xlbf, xrbf, att, bias, du, counts, ssrc, out2, bsum2, bsq2, N, 2);

    // REAL pass (reps=1, identical math to R10-best):
    node_kernel<<<(N + 3) / 4, 256, 0, stream>>>(
        xlbf, xrbf, att, bias, du, counts, ssrc, (float*)d_out, bsum, bsq, N, 1);

    bn_apply_kernel<<<256, 256, 0, stream>>>(
        (float*)d_out, bsum, bsq, gamma, beta, N);
}

// Round 12
// 137.972 us; speedup vs baseline: 1.4301x; 1.4301x over previous
//
#include <hip/hip_runtime.h>
#include <hip/hip_bf16.h>
#include <math.h>

// N=10000, E=160000, DIN=DOUT=256. edge_index is int32 (verified R4/R5).
#define D 256
#define CAP 128           // per-node edge slots; max degree ~45 for this graph
#define NEG_SLOPE 0.2f
#define BN_EPS 1e-5f
#define NBKT 64           // BN column-sum buckets (39 atomics/address — R12 lesson)

typedef __attribute__((ext_vector_type(8))) short bf16x8;
typedef __attribute__((ext_vector_type(8))) unsigned short ushort8;
typedef __attribute__((ext_vector_type(4))) unsigned short ushort4v;
typedef __attribute__((ext_vector_type(4))) float f32x4;
typedef __attribute__((ext_vector_type(2))) float f32x2;

__device__ inline unsigned short f2bf(float f) {
    union { float f; unsigned u; } v; v.f = f;
    unsigned u = v.u;
    unsigned r = u + 0x7FFFu + ((u >> 16) & 1u);   // RNE
    return (unsigned short)(r >> 16);
}
__device__ inline float bf2f(unsigned short u) {
    union { unsigned u; float f; } v; v.u = ((unsigned)u) << 16; return v.f;
}

// unpack 8 bf16 (as 4 u32 pairs) -> 4 f32x2 {even,odd}. One shl + one and per
// pair: single conversion feeding BOTH the dot and the acc update.
__device__ __forceinline__ void unpack8(ushort8 c, f32x2* f) {
    const unsigned* u = (const unsigned*)&c;
    #pragma unroll
    for (int j = 0; j < 4; j++) {
        union { unsigned q; float s; } lo, hi;
        lo.q = u[j] << 16;
        hi.q = u[j] & 0xffff0000u;
        f32x2 v; v.x = lo.s; v.y = hi.s;
        f[j] = v;
    }
}

// async global->LDS, 16B per lane; LDS dest linear, swizzle pre-applied to the
// GLOBAL layout (m173 both-sides-or-neither pattern).
__device__ __forceinline__ void gload16(const void* g, void* l) {
    __builtin_amdgcn_global_load_lds(
        (const __attribute__((address_space(1))) unsigned int*)g,
        (__attribute__((address_space(3))) unsigned int*)l,
        16, 0, 0);
}

// ---------------------------------------------------------------------------
// prep: blocks [0,nzb) zero bsum+bsq+counts+ssrc (ssrc zeroing makes unused
// edge slots point at row 0 -> node gathers need NO guards); [nzb,nzb+128)
// Bt transpose via LDS 32x32 tiles; [nzb+128,...) X fp32->bf16 (XOR-swizzled,
// zero-padded to Mpad rows). Swizzle: k ^= ((row & 7) << 3).
// ---------------------------------------------------------------------------
__global__ void prep_kernel(const float* __restrict__ X,
                            const float* __restrict__ Wl, const float* __restrict__ Wr,
                            int* __restrict__ zero_base, int nzero, int nzb,
                            unsigned short* __restrict__ Bt,
                            unsigned short* __restrict__ Xbf, int N) {
    int b = blockIdx.x;
    if (b < nzb) {
        int idx = b * 256 + threadIdx.x;
        if (idx < nzero) zero_base[idx] = 0;
    } else if (b < nzb + 128) {
        __shared__ float tile[32][33];
        int b2 = b - nzb;                 // 0..127
        const float* W = (b2 < 64) ? Wl : Wr;
        int nbase = (b2 < 64) ? 0 : 256;
        int t2 = b2 & 63;
        int ti = t2 >> 3;                 // k-tile 0..7
        int tj = t2 & 7;                  // n-tile 0..7
        int t = threadIdx.x;
        int r = t >> 3;                   // 0..31
        int c4 = (t & 7) * 4;             // 0..28
        float4 v = *(const float4*)(W + (size_t)(ti * 32 + r) * 256 + tj * 32 + c4);
        tile[r][c4] = v.x; tile[r][c4 + 1] = v.y;
        tile[r][c4 + 2] = v.z; tile[r][c4 + 3] = v.w;
        __syncthreads();
        int nl = t >> 3;
        int n = tj * 32 + nl;
        int k0 = ti * 32 + c4;
        int ks = k0 ^ ((n & 7) << 3);
        ushort4v o;
        o[0] = f2bf(tile[c4][nl]);
        o[1] = f2bf(tile[c4 + 1][nl]);
        o[2] = f2bf(tile[c4 + 2][nl]);
        o[3] = f2bf(tile[c4 + 3][nl]);
        *(ushort4v*)(Bt + (size_t)(nbase + n) * 256 + ks) = o;
    } else {
        int idx = (b - nzb - 128) * 256 + threadIdx.x;   // one 16B chunk (8 elems)
        int row = idx >> 5;
        int k0 = (idx & 31) * 8;
        int ks = k0 ^ ((row & 7) << 3);
        ushort8 v = {0, 0, 0, 0, 0, 0, 0, 0};
        if (row < N) {
            const float* src = X + (size_t)row * 256 + k0;
            float4 f0 = *(const float4*)(src);
            float4 f1 = *(const float4*)(src + 4);
            v[0] = f2bf(f0.x); v[1] = f2bf(f0.y);
            v[2] = f2bf(f0.z); v[3] = f2bf(f0.w);
            v[4] = f2bf(f1.x); v[5] = f2bf(f1.y);
            v[6] = f2bf(f1.z); v[7] = f2bf(f1.w);
        }
        *(ushort8*)(Xbf + (size_t)row * 256 + ks) = v;   // pad rows -> zeros
    }
}

// ---------------------------------------------------------------------------
// gemm_scatter: blocks [0,ngemm) = 64x64 MFMA GEMM tiles with XCD-affinity
// swizzle; staging pure global_load_lds width-16 into linear LDS (swizzle
// baked into the global layout). xl AND xr outputs bf16.
// blocks [ngemm,...) = per-dst edge scatter (into pre-zeroed ssrc).
// ---------------------------------------------------------------------------
__global__ __launch_bounds__(256) void gemm_scatter_kernel(
    const unsigned short* __restrict__ Xbf, const unsigned short* __restrict__ Bt,
    const float* __restrict__ bl, const float* __restrict__ br,
    const int* __restrict__ ei, int* __restrict__ counts, int* __restrict__ ssrc,
    unsigned short* __restrict__ xlbf, unsigned short* __restrict__ xrbf,
    int M, int E, int N, int ngemm, int nMtiles)
{
    if ((int)blockIdx.x >= ngemm) {
        int e = (blockIdx.x - ngemm) * 256 + threadIdx.x;
        if (e < E + N) {
            int src, dst;
            if (e < E) { src = ei[e]; dst = ei[E + e]; }
            else       { src = dst = e - E; }          // self-loop
            int pos = atomicAdd(&counts[dst], 1);
            if (pos < CAP) ssrc[dst * CAP + pos] = src;
        }
        return;
    }

    const int b = blockIdx.x;
    const int r = (b & 7) + 8 * (b >> 6);           // row-tile
    const int c = (b >> 3) & 7;                     // col-tile 0..7
    if (r >= nMtiles) return;

    __shared__ __align__(16) unsigned short As[64 * 128];
    __shared__ __align__(16) unsigned short Bs[64 * 128];

    const int tid = threadIdx.x;
    const int wave = tid >> 6, lane = tid & 63;
    const int m_l = lane & 15, quad = lane >> 4;
    const int row0 = r * 64;
    const int n0 = c * 64;
    const int sw = (m_l & 7) << 3;

    f32x4 acc[4] = {};

    for (int k0 = 0; k0 < 256; k0 += 128) {
        __syncthreads();
        #pragma unroll
        for (int i = 0; i < 4; i++) {
            int L = (tid + i * 256) * 16;
            int rr = L >> 8;
            int cb = L & 255;
            gload16((const char*)Xbf + (size_t)(row0 + rr) * 512 + (size_t)k0 * 2 + cb,
                    (char*)As + L);
            gload16((const char*)Bt + (size_t)(n0 + rr) * 512 + (size_t)k0 * 2 + cb,
                    (char*)Bs + L);
        }
        __syncthreads();

        #pragma unroll
        for (int kk0 = 0; kk0 < 128; kk0 += 32) {
            int ka = (kk0 + quad * 8) ^ sw;
            bf16x8 a = *(const bf16x8*)&As[(wave * 16 + m_l) * 128 + ka];
            #pragma unroll
            for (int cc = 0; cc < 4; cc++) {
                bf16x8 bv = *(const bf16x8*)&Bs[(cc * 16 + m_l) * 128 + ka];
                acc[cc] = __builtin_amdgcn_mfma_f32_16x16x32_bf16(a, bv, acc[cc], 0, 0, 0);
            }
        }
    }

    const bool isl = (n0 < 256);
    #pragma unroll
    for (int cc = 0; cc < 4; cc++) {
        int col = n0 + cc * 16 + m_l;
        int col8 = col & 255;
        float bv = isl ? bl[col8] : br[col8];
        #pragma unroll
        for (int rr = 0; rr < 4; rr++) {
            int row = row0 + wave * 16 + quad * 4 + rr;
            if (row < M) {
                float v = acc[cc][rr] + bv;
                if (isl) xlbf[(size_t)row * 256 + col8] = f2bf(v);
                else     xrbf[(size_t)row * 256 + col8] = f2bf(v);
            }
        }
    }
}

// ---------------------------------------------------------------------------
// node: ONE NODE PER WAVE, direct-exp softmax, bf16 xr (R10-best structure).
// R12 VALU cuts: (1) ssrc pre-zeroed -> ALL gather guards removed (invalid
// slots read row 0; the -INF score masks already zero their contribution
// exactly); (2) gathered bf16 unpacked ONCE into f32x2 arrays reused by dot
// and acc-update; (3) dot/leaky/acc in packed f32x2 form (leaky as
// max(h, 0.2h) — bit-identical) to enable v_pk_*_f32 codegen.
// ---------------------------------------------------------------------------
__device__ __forceinline__ float dot8pk(const f32x2* f, const f32x2* b2,
                                        const f32x2* a2) {
    f32x2 s2 = {0.f, 0.f};
    #pragma unroll
    for (int j = 0; j < 4; j++) {
        f32x2 h = f[j] + b2[j];
        f32x2 l = __builtin_elementwise_max(h, h * 0.2f);   // leaky, bit-identical
        s2 += l * a2[j];
    }
    return s2.x + s2.y;
}

__global__ __launch_bounds__(256, 4) void node_kernel(
    const unsigned short* __restrict__ xlbf, const unsigned short* __restrict__ xrbf,
    const float* __restrict__ att, const float* __restrict__ bias,
    const float* __restrict__ du, const int* __restrict__ counts,
    const int* __restrict__ ssrc, float* __restrict__ out,
    float* __restrict__ bsum, float* __restrict__ bsq, int N)
{
    __shared__ float ls[4][256];

    const int wave = threadIdx.x >> 6, lane = threadIdx.x & 63;
    const int i = blockIdx.x * 4 + wave;
    const bool valid = (i < N);
    const int hl = lane & 31;
    const int sid = lane >> 5;                  // stream 0 or 1

    int cnt = valid ? counts[i] : 0;
    if (cnt > CAP) cnt = CAP;
    const int start = i * CAP, end = start + cnt;

    const ushort8 z8 = {0, 0, 0, 0, 0, 0, 0, 0};
    const float4 attA = ((const float4*)att)[hl * 2];
    const float4 attB = ((const float4*)att)[hl * 2 + 1];
    f32x2 a2[4];
    a2[0].x = attA.x; a2[0].y = attA.y; a2[1].x = attA.z; a2[1].y = attA.w;
    a2[2].x = attB.x; a2[2].y = attB.y; a2[3].x = attB.z; a2[3].y = attB.w;

    ushort8 xrv = valid ? *(const ushort8*)(xrbf + (size_t)i * D + hl * 8) : z8;
    f32x2 b2[4];
    unpack8(xrv, b2);

    float lsum = 0.f;
    f32x2 acc2[4] = {};
    const unsigned short* xb = xlbf + hl * 8;

    for (int cs = start; cs < end; cs += 64) {
        const int cend = (end < cs + 64) ? end : cs + 64;
        int srcv = ssrc[cs + lane];             // in-bounds: cs+lane < start+CAP
        int e = cs + sid;

        // unconditional first prefetch quad (unused slots -> row 0, safe)
        ushort8 p0, p1, p2, p3;
        {
            int a0 = __shfl(srcv, sid);
            int a1 = __shfl(srcv, sid + 2);
            int a2i = __shfl(srcv, sid + 4);
            int a3 = __shfl(srcv, sid + 6);
            p0 = *(const ushort8*)(xb + (size_t)a0 * D);
            p1 = *(const ushort8*)(xb + (size_t)a1 * D);
            p2 = *(const ushort8*)(xb + (size_t)a2i * D);
            p3 = *(const ushort8*)(xb + (size_t)a3 * D);
        }

        while (e < cend) {
            ushort8 c0 = p0, c1 = p1, c2 = p2, c3 = p3;
            bool v1 = (e + 2 < cend), v2 = (e + 4 < cend), v3 = (e + 6 < cend);
            int en = e + 8;
            {
                int on = (en - cs) & 63;
                int a0 = __shfl(srcv, on);
                int a1 = __shfl(srcv, on + 2);
                int a2i = __shfl(srcv, on + 4);
                int a3 = __shfl(srcv, on + 6);
                p0 = *(const ushort8*)(xb + (size_t)a0 * D);
                p1 = *(const ushort8*)(xb + (size_t)a1 * D);
                p2 = *(const ushort8*)(xb + (size_t)a2i * D);
                p3 = *(const ushort8*)(xb + (size_t)a3 * D);
            }

            // single unpack per edge, reused by dot AND acc update
            f32x2 f0[4], f1[4], f2[4], f3[4];
            unpack8(c0, f0); unpack8(c1, f1);
            unpack8(c2, f2); unpack8(c3, f3);

            float s0 = dot8pk(f0, b2, a2);
            float s1 = dot8pk(f1, b2, a2);
            float s2 = dot8pk(f2, b2, a2);
            float s3 = dot8pk(f3, b2, a2);

            #pragma unroll
            for (int off = 1; off < 32; off <<= 1) {    // within half-wave
                s0 += __shfl_xor(s0, off);
                s1 += __shfl_xor(s1, off);
                s2 += __shfl_xor(s2, off);
                s3 += __shfl_xor(s3, off);
            }
            if (!v1) s1 = -INFINITY;                    // exp(-inf) = 0
            if (!v2) s2 = -INFINITY;
            if (!v3) s3 = -INFINITY;

            float e0e = __expf(s0);
            float e1e = __expf(s1);
            float e2e = __expf(s2);
            float e3e = __expf(s3);
            lsum += e0e + e1e + e2e + e3e;
            #pragma unroll
            for (int j = 0; j < 4; j++) {
                acc2[j] += e0e * f0[j] + e1e * f1[j]
                         + e2e * f2[j] + e3e * f3[j];
            }
            e = en;
        }
    }

    // du row load: latency hides under the combine shuffles
    float4 uA, uB;
    if (valid && lane < 32) {
        uA = ((const float4*)(du + (size_t)i * D))[hl * 2];
        uB = ((const float4*)(du + (size_t)i * D))[hl * 2 + 1];
    }

    // combine the two half-wave streams (plain adds — direct exp)
    lsum += __shfl_xor(lsum, 32);
    #pragma unroll
    for (int j = 0; j < 4; j++) {
        acc2[j][0] += __shfl_xor(acc2[j][0], 32);
        acc2[j][1] += __shfl_xor(acc2[j][1], 32);
    }

    // epilogue: bias+ReLU+dropout, store, BN staging
    // dim order: acc2[j][0] = dim hl*8+2j, acc2[j][1] = dim hl*8+2j+1
    float ov[8];
    if (lane < 32) {
        if (valid) {
            float inv = 1.f / lsum;
            float4 biA = ((const float4*)bias)[hl * 2];
            float4 biB = ((const float4*)bias)[hl * 2 + 1];
            float4 oA, oB;
            oA.x = fmaxf(acc2[0][0] * inv + biA.x, 0.f); oA.x = (uA.x >= 0.5f) ? 2.f * oA.x : 0.f;
            oA.y = fmaxf(acc2[0][1] * inv + biA.y, 0.f); oA.y = (uA.y >= 0.5f) ? 2.f * oA.y : 0.f;
            oA.z = fmaxf(acc2[1][0] * inv + biA.z, 0.f); oA.z = (uA.z >= 0.5f) ? 2.f * oA.z : 0.f;
            oA.w = fmaxf(acc2[1][1] * inv + biA.w, 0.f); oA.w = (uA.w >= 0.5f) ? 2.f * oA.w : 0.f;
            oB.x = fmaxf(acc2[2][0] * inv + biB.x, 0.f); oB.x = (uB.x >= 0.5f) ? 2.f * oB.x : 0.f;
            oB.y = fmaxf(acc2[2][1] * inv + biB.y, 0.f); oB.y = (uB.y >= 0.5f) ? 2.f * oB.y : 0.f;
            oB.z = fmaxf(acc2[3][0] * inv + biB.z, 0.f); oB.z = (uB.z >= 0.5f) ? 2.f * oB.z : 0.f;
            oB.w = fmaxf(acc2[3][1] * inv + biB.w, 0.f); oB.w = (uB.w >= 0.5f) ? 2.f * oB.w : 0.f;
            ((float4*)(out + (size_t)i * D))[hl * 2] = oA;
            ((float4*)(out + (size_t)i * D))[hl * 2 + 1] = oB;
            ov[0] = oA.x; ov[1] = oA.y; ov[2] = oA.z; ov[3] = oA.w;
            ov[4] = oB.x; ov[5] = oB.y; ov[6] = oB.z; ov[7] = oB.w;
        } else {
            #pragma unroll
            for (int k = 0; k < 8; k++) ov[k] = 0.f;
        }
        #pragma unroll
        for (int k = 0; k < 8; k++) ls[wave][hl * 8 + k] = ov[k];
    }
    __syncthreads();

    // per-block column reduction over the 4 rows, one atomic pair per column
    {
        int t = threadIdx.x;
        float s = 0.f, s2 = 0.f;
        #pragma unroll
        for (int w = 0; w < 4; w++) {
            float v = ls[w][t];
            s += v; s2 += v * v;
        }
        int bkt = (blockIdx.x & (NBKT - 1)) * 256 + t;
        atomicAdd(&bsum[bkt], s);
        atomicAdd(&bsq[bkt], s2);
    }
}

// ---------------------------------------------------------------------------
// bn_apply: 256 blocks, bucket-reduce prologue + in-place FMA.
// ---------------------------------------------------------------------------
__global__ __launch_bounds__(256) void bn_apply_kernel(
    float* __restrict__ out,
    const float* __restrict__ bsum, const float* __restrict__ bsq,
    const float* __restrict__ gamma, const float* __restrict__ beta, int N)
{
    __shared__ float scaleL[256], shiftL[256];
    const int t = threadIdx.x;
    float s = 0.f, s2 = 0.f;
    #pragma unroll 8
    for (int b = 0; b < NBKT; b++) {
        s += bsum[b * 256 + t];
        s2 += bsq[b * 256 + t];
    }
    float invN = 1.f / (float)N;
    float mean = s * invN;
    float var = s2 * invN - mean * mean;
    float rs = rsqrtf(var + BN_EPS);
    float sc = gamma[t] * rs;
    scaleL[t] = sc;
    shiftL[t] = beta[t] - mean * sc;
    __syncthreads();

    const int c4 = t & 63;
    float4 scv, shv;
    scv.x = scaleL[c4 * 4];     shv.x = shiftL[c4 * 4];
    scv.y = scaleL[c4 * 4 + 1]; shv.y = shiftL[c4 * 4 + 1];
    scv.z = scaleL[c4 * 4 + 2]; shv.z = shiftL[c4 * 4 + 2];
    scv.w = scaleL[c4 * 4 + 3]; shv.w = shiftL[c4 * 4 + 3];

    for (int row = blockIdx.x * 4 + (t >> 6); row < N; row += gridDim.x * 4) {
        float4 v = ((float4*)(out + (size_t)row * D))[c4];
        v.x = v.x * scv.x + shv.x;
        v.y = v.y * scv.y + shv.y;
        v.z = v.z * scv.z + shv.z;
        v.w = v.w * scv.w + shv.w;
        ((float4*)(out + (size_t)row * D))[c4] = v;
    }
}

// ---------------------------------------------------------------------------
extern "C" void kernel_launch(void* const* d_in, const int* in_sizes, int n_in,
                              void* d_out, int out_size, void* d_ws, size_t ws_size,
                              hipStream_t stream) {
    const float* x     = (const float*)d_in[0];
    const int*   ei    = (const int*)d_in[1];
    const float* Wl    = (const float*)d_in[2];
    const float* bl    = (const float*)d_in[3];
    const float* Wr    = (const float*)d_in[4];
    const float* br    = (const float*)d_in[5];
    const float* att   = (const float*)d_in[6];
    const float* bias  = (const float*)d_in[7];
    const float* gamma = (const float*)d_in[8];
    const float* beta  = (const float*)d_in[9];
    const float* du    = (const float*)d_in[10];

    const int N = in_sizes[0] / D;       // 10000
    const int E = in_sizes[1] / 2;       // 160000
    const int Mpad = (N + 63) & ~63;     // 10048

    // workspace layout (4-byte word units)
    int* ws = (int*)d_ws;
    size_t off = 0;
    unsigned short* xrbf = (unsigned short*)(ws + off); off += (size_t)N * D / 2;
    unsigned short* xlbf = (unsigned short*)(ws + off); off += (size_t)N * D / 2;
    unsigned short* Xbf  = (unsigned short*)(ws + off); off += (size_t)Mpad * D / 2;
    unsigned short* Bt   = (unsigned short*)(ws + off); off += 512 * 256 / 2;
    // contiguous zeroed region (zeroed by prep_kernel blocks [0,nzb)):
    float* bsum     = (float*)(ws + off); off += NBKT * 256;
    float* bsq      = (float*)(ws + off); off += NBKT * 256;
    int*   counts   = ws + off;           off += N;
    int*   ssrc     = ws + off;           off += (size_t)N * CAP;   // zeroed -> guard-free gathers
    int nzero = 2 * NBKT * 256 + N + N * CAP;   // 1322768 words (~5.3 MB)
    int nzb = (nzero + 255) / 256;              // 5168 zero blocks

    int nconv = (Mpad * 32) / 256;       // 1256 blocks, 8 elems/thread
    prep_kernel<<<nzb + 128 + nconv, 256, 0, stream>>>(
        x, Wl, Wr, (int*)bsum, nzero, nzb, Bt, Xbf, N);

    int nMtiles = (N + 63) / 64;         // 157
    int nMgroups = (nMtiles + 7) / 8;    // 20
    int ngemm = nMgroups * 64;           // 1280 gemm blocks (24 idle)
    int nscat = (E + N + 255) / 256;     // 665
    gemm_scatter_kernel<<<ngemm + nscat, 256, 0, stream>>>(
        Xbf, Bt, bl, br, ei, counts, ssrc, xlbf, xrbf, N, E, N, ngemm, nMtiles);

    node_kernel<<<(N + 3) / 4, 256, 0, stream>>>(
        xlbf, xrbf, att, bias, du, counts, ssrc, (float*)d_out, bsum, bsq, N);

    bn_apply_kernel<<<256, 256, 0, stream>>>(
        (float*)d_out, bsum, bsq, gamma, beta, N);
}